// Round 15
// baseline (121.132 us; speedup 1.0000x reference)
//
#include <hip/hip_runtime.h>
#include <math.h>

#define HH 512
#define WW 512
#define HB 64        // band height (8 bands per plane -> grid 992)
#define KR 4         // output rows per group
#define SUB 138      // 8B slots per sub-array; 138%16==10 -> <=2-way write
                     // conflicts (free, m136); 132 slots needed (128+halo)
#define ROWU2 (4 * SUB)    // uint2 per row-tile
#define TILEU2 (4 * ROWU2) // uint2 per buffer (17664 B)

// R15 = R14 with the compile fix (cvt_pkrtz returns __fp16 vec2 -> bit_cast).
// R14 design rationale:
//  1. f16x2-packed tiles: 4 fields = 2 dwords/column (cvt_pkrtz on stage,
//     ds_read_b64 taps). Tile 35.3->17.7KB => DOUBLE-buffer at R12's 35.3KB
//     total footprint with R13's single barrier per group. Numerics: f16 RNE
//     noise ~2e-3/point is zero-mean; final-mean bias ~1e-4 << 1.98e-2.
//  2. H-pass in packed f16 FMA (v_pk_fma_f16): no unpack ops, acc regs halve.
//     Vertical stays f32; SSIM ratio in f32.
//  3. static 16-slot ring (4-group unroll, all indices compile-time): no
//     rotate movs; prefetch writes ring slots directly; wave-uniform guards.

typedef float v2f __attribute__((ext_vector_type(2)));
typedef _Float16 h2 __attribute__((ext_vector_type(2)));

__device__ __forceinline__ void bar_lgkm() {
  asm volatile("s_waitcnt lgkmcnt(0)" ::: "memory");
  __builtin_amdgcn_s_barrier();
  __builtin_amdgcn_sched_barrier(0);
}

__device__ __forceinline__ unsigned pk16(float a, float b) {
  return __builtin_bit_cast(unsigned, __builtin_amdgcn_cvt_pkrtz(a, b));
}

__global__ __launch_bounds__(512, 1)
void ssim_main(const float* __restrict__ Pg, const float* __restrict__ Tg,
               float* __restrict__ partial) {
  __shared__ __align__(16) uint2 S2[2 * TILEU2];   // 35328 B
  __shared__ float wsum[8];

  const int tid = threadIdx.x;            // vertical pass: column 0..511
  const int blk = blockIdx.x;
  const int plane = blk >> 3;
  const int band  = blk & 7;
  const int o0 = band * HB;               // first output row of band
  const float* __restrict__ P = Pg + (size_t)plane * (HH * WW);
  const float* __restrict__ T = Tg + (size_t)plane * (HH * WW);

  // zero both buffers once: halo slots (0,1 and 130..137 per sub-array) must
  // stay 0 forever; interior slots are fully overwritten every group.
  {
    const uint2 z = make_uint2(0u, 0u);
    for (int idx = tid; idx < 2 * TILEU2; idx += 512) S2[idx] = z;
  }

  // Gaussian weights, computed in double then rounded to f32 (matches jnp f32)
  float w[11];
  {
    double g[11], s = 0.0;
#pragma unroll
    for (int k = 0; k < 11; ++k) {
      double c = (double)(k - 5);
      g[k] = exp(-c * c / 4.5);
      s += g[k];
    }
#pragma unroll
    for (int k = 0; k < 11; ++k)
      w[k] = __uint_as_float(__builtin_amdgcn_readfirstlane(
                 __float_as_uint((float)(g[k] / s))));
  }
  // f16 weight pairs for the packed H-pass
  h2 wh[11];
#pragma unroll
  for (int k = 0; k < 11; ++k) {
    const _Float16 hw = (_Float16)w[k];
    wh[k][0] = hw; wh[k][1] = hw;
  }

  float sum = 0.f;
  const int jr = tid >> 7;                // H-pass: row within group (0..3)
  const int q  = tid & 127;               // H-pass: 4-col block (cols 4q..4q+3)
  uint2* const rdbase = &S2[jr * ROWU2 + q + 2];
  uint2* const wrbase = &S2[(tid & 3) * SUB + (tid >> 2) + 2];

  // ---- static 16-slot ring: input row with R_rel = r-(o0-5) lives in slot
  // R_rel & 15. Group gi uses R_rel 4gi..4gi+13; 4-group unroll makes every
  // index compile-time.
  float rp[16], rt[16];
  if (o0 > 0) {
#pragma unroll
    for (int j = 0; j < 10; ++j) {
      rp[j] = P[(size_t)(o0 - 5 + j) * WW + tid];
      rt[j] = T[(size_t)(o0 - 5 + j) * WW + tid];
    }
  } else {
#pragma unroll
    for (int j = 0; j < 10; ++j) {
      const int r = o0 - 5 + j;
      const bool v = r >= 0;
      rp[j] = v ? P[(size_t)r * WW + tid] : 0.f;
      rt[j] = v ? T[(size_t)r * WW + tid] : 0.f;
    }
  }
#pragma unroll
  for (int i = 0; i < 4; ++i) {           // rows o0+5..o0+8, always valid
    rp[10 + i] = P[(size_t)(o0 + 5 + i) * WW + tid];
    rt[10 + i] = T[(size_t)(o0 + 5 + i) * WW + tid];
  }

  bar_lgkm();   // zero-init visible before the first stage write

#define GROUP(GB, GI) {                                                    \
    v2f apt[KR], asq[KR];                                                  \
    { const v2f z = {0.f, 0.f};                                            \
      _Pragma("unroll")                                                    \
      for (int j = 0; j < KR; ++j) { apt[j] = z; asq[j] = z; } }           \
    _Pragma("unroll")                                                      \
    for (int ri = 0; ri < 14; ++ri) {                                      \
      const float p_ = rp[(4 * (GI) + ri) & 15];                           \
      const float t_ = rt[(4 * (GI) + ri) & 15];                           \
      const v2f pt  = {p_, t_};                                            \
      const v2f q23 = {fmaf(t_, t_, p_ * p_), p_ * t_};                    \
      _Pragma("unroll")                                                    \
      for (int j = 0; j < KR; ++j)                                         \
        if (ri - j >= 0 && ri - j <= 10) {                                 \
          const float wk = w[ri - j];                                      \
          const v2f wv = {wk, wk};                                         \
          apt[j] = __builtin_elementwise_fma(wv, pt,  apt[j]);             \
          asq[j] = __builtin_elementwise_fma(wv, q23, asq[j]);             \
        }                                                                  \
    }                                                                      \
    { /* prefetch next group's 4 rows straight into ring slots */          \
      const int prow = o0 + 4 * ((GB) + (GI)) + 9;                         \
      if (prow + 3 < HH) {                                                 \
        _Pragma("unroll")                                                  \
        for (int i = 0; i < 4; ++i) {                                      \
          rp[(4 * (GI) + 14 + i) & 15] = P[(size_t)(prow + i) * WW + tid]; \
          rt[(4 * (GI) + 14 + i) & 15] = T[(size_t)(prow + i) * WW + tid]; \
        }                                                                  \
      } else {                                                             \
        _Pragma("unroll")                                                  \
        for (int i = 0; i < 4; ++i) {                                      \
          const int r = prow + i;                                          \
          const bool v = r < HH;                                           \
          rp[(4 * (GI) + 14 + i) & 15] =                                   \
              v ? P[(size_t)r * WW + tid] : 0.f;                           \
          rt[(4 * (GI) + 14 + i) & 15] =                                   \
              v ? T[(size_t)r * WW + tid] : 0.f;                           \
        }                                                                  \
      } }                                                                  \
    /* stage into buffer GI&1 (other buffer may still be read: dist-2 */   \
    /* reuse protected by the previous barrier, R13 argument) */           \
    _Pragma("unroll")                                                      \
    for (int j = 0; j < KR; ++j)                                           \
      wrbase[((GI) & 1) * TILEU2 + j * ROWU2] =                            \
          make_uint2(pk16(apt[j][0], apt[j][1]),                           \
                     pk16(asq[j][0], asq[j][1]));                          \
    bar_lgkm();                                                            \
    /* H-pass: packed f16 FMAs, 14 imm-offset b64 taps, 4 cols/thread */   \
    h2 hpt[4], hsq[4];                                                     \
    { const h2 z = {(_Float16)0.f, (_Float16)0.f};                         \
      _Pragma("unroll")                                                    \
      for (int m = 0; m < 4; ++m) { hpt[m] = z; hsq[m] = z; } }            \
    _Pragma("unroll")                                                      \
    for (int k = 0; k < 14; ++k) {                                         \
      const int d = k - 5;                                                 \
      const int s = d & 3;                                                 \
      const int o = (d - s) >> 2;                                          \
      const uint2 vv = rdbase[((GI) & 1) * TILEU2 + s * SUB + o];          \
      const h2 va = __builtin_bit_cast(h2, vv.x);                          \
      const h2 vb = __builtin_bit_cast(h2, vv.y);                          \
      _Pragma("unroll")                                                    \
      for (int m = 0; m < 4; ++m)                                          \
        if (k - m >= 0 && k - m <= 10) {                                   \
          hpt[m] = __builtin_elementwise_fma(wh[k - m], va, hpt[m]);       \
          hsq[m] = __builtin_elementwise_fma(wh[k - m], vb, hsq[m]);       \
        }                                                                  \
      if (k == 7) __builtin_amdgcn_sched_barrier(0);                       \
    }                                                                      \
    _Pragma("unroll")                                                      \
    for (int m = 0; m < 4; ++m) {                                          \
      const float hmp = (float)hpt[m][0], hmt = (float)hpt[m][1];          \
      const float s2f = (float)hsq[m][0], scf = (float)hsq[m][1];          \
      const float mp2 = hmp * hmp, mt2 = hmt * hmt, mct = hmp * hmt;       \
      const float ssum = fmaxf(s2f - mp2 - mt2, 0.f);                      \
      const float scv = scf - mct;                                         \
      const float num = fmaf(2.f, mct, 1.0e-4f) * fmaf(2.f, scv, 9.0e-4f); \
      const float den = (mp2 + mt2 + 1.0e-4f) * (ssum + 9.0e-4f);          \
      sum += num * __builtin_amdgcn_rcpf(den);                             \
    }                                                                      \
  }

  for (int gb = 0; gb < 16; gb += 4) {    // 16 groups, unrolled x4
    GROUP(gb, 0)
    GROUP(gb, 1)
    GROUP(gb, 2)
    GROUP(gb, 3)
  }
#undef GROUP

  // block reduction of ssim partial sum
#pragma unroll
  for (int off = 32; off > 0; off >>= 1) sum += __shfl_down(sum, off, 64);
  if ((tid & 63) == 0) wsum[tid >> 6] = sum;
  __syncthreads();
  if (tid == 0) {
    float s = 0.f;
#pragma unroll
    for (int k2 = 0; k2 < 8; ++k2) s += wsum[k2];
    partial[blk] = s;
  }
}

__global__ void ssim_fin(const float* __restrict__ partial,
                         float* __restrict__ out, int n) {
  __shared__ double ws[4];
  double s = 0.0;
  for (int idx = threadIdx.x; idx < n; idx += 256) s += (double)partial[idx];
#pragma unroll
  for (int off = 32; off > 0; off >>= 1) s += __shfl_down(s, off, 64);
  if ((threadIdx.x & 63) == 0) ws[threadIdx.x >> 6] = s;
  __syncthreads();
  if (threadIdx.x == 0) {
    double tt = ws[0] + ws[1] + ws[2] + ws[3];
    out[0] = (float)(1.0 - tt / 32505856.0);
  }
}

extern "C" void kernel_launch(void* const* d_in, const int* in_sizes, int n_in,
                              void* d_out, int out_size, void* d_ws, size_t ws_size,
                              hipStream_t stream) {
  const float* pred = (const float*)d_in[0];
  const float* tgt  = (const float*)d_in[1];
  float* out        = (float*)d_out;
  float* partial    = (float*)d_ws;   // 992 floats of scratch

  ssim_main<<<dim3(992), dim3(512), 0, stream>>>(pred, tgt, partial);
  ssim_fin<<<dim3(1), dim3(256), 0, stream>>>(partial, out, 992);
}

// Round 16
// 94.503 us; speedup vs baseline: 1.2818x; 1.2818x over previous
//
#include <hip/hip_runtime.h>
#include <math.h>

#define HH 512
#define WW 512
#define HB 64        // band height (8 bands per plane -> grid 992)
#define KR 4         // output rows per group
#define SUB 132      // uint2 slots per sub-array: exactly 2+128+2 (halo+cols);
                     // 2*132 mod 32 == 8 -> write banks s*8+{0..14} = every
                     // bank 2-way per 32-lane phase = FREE (m136). R15's
                     // SUB=138 gave 20 -> colliding sets -> 2M conflicts.
#define ROWU2 (4 * SUB)     // 528 uint2 per row-tile
#define TILEU2 (4 * ROWU2)  // 2112 uint2 = 16896 B per buffer

// R16 = R12's proven core (rotating reg-ring VGPR=36, imm-offset taps, light
// barriers) + f16-packed DOUBLE-buffered tiles at R12's total LDS footprint:
//  - 2 x 16.9KB buffers = 33.8KB -> R13's single-barrier-per-group schedule
//    (16 barriers/band instead of 32) without R13's occupancy loss.
//  - taps become ds_read_b64 (half the LDS pipe cycles of b128).
//  - f16 numerics validated in R15: absmax 0.0039 << 0.0198 threshold.
//  - R15's VGPR=120 blowup avoided: keep R12's rotating ring (not the 4x
//    static ring), unroll groups only x2 for compile-time buffer parity.

typedef float v2f __attribute__((ext_vector_type(2)));
typedef _Float16 h2 __attribute__((ext_vector_type(2)));

__device__ __forceinline__ void bar_lgkm() {
  asm volatile("s_waitcnt lgkmcnt(0)" ::: "memory");
  __builtin_amdgcn_s_barrier();
  __builtin_amdgcn_sched_barrier(0);
}

__device__ __forceinline__ unsigned pk16(float a, float b) {
  return __builtin_bit_cast(unsigned, __builtin_amdgcn_cvt_pkrtz(a, b));
}

__global__ __launch_bounds__(512, 1)
void ssim_main(const float* __restrict__ Pg, const float* __restrict__ Tg,
               float* __restrict__ partial) {
  __shared__ __align__(16) uint2 S2[2 * TILEU2];   // 33792 B
  __shared__ float wsum[8];

  const int tid = threadIdx.x;            // vertical pass: column 0..511
  const int blk = blockIdx.x;
  const int plane = blk >> 3;
  const int band  = blk & 7;
  const int o0 = band * HB;               // first output row of band
  const float* __restrict__ P = Pg + (size_t)plane * (HH * WW);
  const float* __restrict__ T = Tg + (size_t)plane * (HH * WW);

  // zero both buffers once: halo slots (0,1,130,131 per sub-array) must stay
  // 0 forever; interior slots 2..129 are fully overwritten every group.
  {
    const uint2 z = make_uint2(0u, 0u);
    for (int idx = tid; idx < 2 * TILEU2; idx += 512) S2[idx] = z;
  }

  // Gaussian weights, computed in double then rounded to f32 (matches jnp f32)
  float w[11];
  {
    double g[11], s = 0.0;
#pragma unroll
    for (int k = 0; k < 11; ++k) {
      double c = (double)(k - 5);
      g[k] = exp(-c * c / 4.5);
      s += g[k];
    }
#pragma unroll
    for (int k = 0; k < 11; ++k)
      w[k] = __uint_as_float(__builtin_amdgcn_readfirstlane(
                 __float_as_uint((float)(g[k] / s))));
  }
  // f16 weight pairs for the packed H-pass
  h2 wh[11];
#pragma unroll
  for (int k = 0; k < 11; ++k) {
    const _Float16 hw = (_Float16)w[k];
    wh[k][0] = hw; wh[k][1] = hw;
  }

  float sum = 0.f;
  const int jr = tid >> 7;                // H-pass: row within group (0..3)
  const int q  = tid & 127;               // H-pass: 4-col block (cols 4q..4q+3)
  uint2* const rdbase = &S2[jr * ROWU2 + q + 2];
  uint2* const wrbase = &S2[(tid & 3) * SUB + (tid >> 2) + 2];

  // ---- rotating register ring (R12-proven): pr/tr[i] = input row rbase+i
  // (i=0..9); pn/tn = rows rbase+10..13 in flight. rbase = o0 + g - 5.
  float pr[10], tr[10], pn[4], tn[4];
#pragma unroll
  for (int i = 0; i < 10; ++i) {
    const int r = o0 - 5 + i;
    const bool v = (r >= 0);              // r <= o0+4 <= 452 < HH always
    pr[i] = v ? P[(size_t)r * WW + tid] : 0.f;
    tr[i] = v ? T[(size_t)r * WW + tid] : 0.f;
  }
#pragma unroll
  for (int i = 0; i < 4; ++i) {
    const int r = o0 + 5 + i;             // always in [5, 461]
    pn[i] = P[(size_t)r * WW + tid];
    tn[i] = T[(size_t)r * WW + tid];
  }

  bar_lgkm();   // zero-init visible before the first stage write

#define VACC(RI, PV, TV) {                                                 \
      const float p_ = (PV), t_ = (TV);                                   \
      const v2f pt  = {p_, t_};                                           \
      const v2f q23 = {fmaf(t_, t_, p_ * p_), p_ * t_};                   \
      _Pragma("unroll")                                                   \
      for (int j = 0; j < KR; ++j) {                                      \
        if ((RI) - j >= 0 && (RI) - j <= 10) {                            \
          const float wk = w[(RI) - j];                                   \
          const v2f wv = {wk, wk};                                        \
          apt[j] = __builtin_elementwise_fma(wv, pt,  apt[j]);            \
          asq[j] = __builtin_elementwise_fma(wv, q23, asq[j]);            \
        }                                                                 \
      }                                                                   \
    }

// One group: V (f32) -> rotate+prefetch -> stage f16 into buf B -> ONE
// barrier -> H-pass (packed f16) + SSIM (f32).
// Buffer-reuse safety (R13 argument, proven): stage_i(buf B) happens after
// this wave passed bar_{i-1}; every wave's H_{i-2}(buf B) reads completed
// (lgkmcnt(0)) before it reached bar_{i-2} < bar_{i-1}. 
#define GROUP(G, B) {                                                      \
    v2f apt[KR], asq[KR];                                                  \
    { const v2f z = {0.f, 0.f};                                            \
      _Pragma("unroll")                                                    \
      for (int j = 0; j < KR; ++j) { apt[j] = z; asq[j] = z; } }           \
    _Pragma("unroll")                                                      \
    for (int ri = 0; ri < 10; ++ri) VACC(ri, pr[ri], tr[ri]);              \
    _Pragma("unroll")                                                      \
    for (int i = 0; i < 4; ++i) VACC(10 + i, pn[i], tn[i]);                \
    /* rotate ring by 4, issue next group's 4-row prefetch */              \
    _Pragma("unroll")                                                      \
    for (int i = 0; i < 6; ++i) { pr[i] = pr[i + 4]; tr[i] = tr[i + 4]; }  \
    _Pragma("unroll")                                                      \
    for (int i = 0; i < 4; ++i) { pr[6 + i] = pn[i]; tr[6 + i] = tn[i]; }  \
    _Pragma("unroll")                                                      \
    for (int i = 0; i < 4; ++i) {                                          \
      const int r = o0 + (G) + 9 + i;                                      \
      if (r < HH) {                                                        \
        pn[i] = P[(size_t)r * WW + tid];                                   \
        tn[i] = T[(size_t)r * WW + tid];                                   \
      } else {                                                             \
        pn[i] = 0.f; tn[i] = 0.f;                                          \
      }                                                                    \
    }                                                                      \
    /* stage f16x2 pairs into buffer B */                                  \
    _Pragma("unroll")                                                      \
    for (int j = 0; j < KR; ++j)                                           \
      wrbase[(B) * TILEU2 + j * ROWU2] =                                   \
          make_uint2(pk16(apt[j][0], apt[j][1]),                           \
                     pk16(asq[j][0], asq[j][1]));                          \
    bar_lgkm();        /* single barrier: stage_B visible to all waves */  \
    /* H-pass: packed f16 FMAs, 14 imm-offset b64 taps, 4 cols/thread */   \
    h2 hpt[4], hsq[4];                                                     \
    { const h2 z = {(_Float16)0.f, (_Float16)0.f};                         \
      _Pragma("unroll")                                                    \
      for (int m = 0; m < 4; ++m) { hpt[m] = z; hsq[m] = z; } }            \
    _Pragma("unroll")                                                      \
    for (int k = 0; k < 14; ++k) {                                         \
      const int d = k - 5;                                                 \
      const int s = d & 3;                                                 \
      const int o = (d - s) >> 2;                                          \
      const uint2 vv = rdbase[(B) * TILEU2 + s * SUB + o];                 \
      const h2 va = __builtin_bit_cast(h2, vv.x);                          \
      const h2 vb = __builtin_bit_cast(h2, vv.y);                          \
      _Pragma("unroll")                                                    \
      for (int m = 0; m < 4; ++m)                                          \
        if (k - m >= 0 && k - m <= 10) {                                   \
          hpt[m] = __builtin_elementwise_fma(wh[k - m], va, hpt[m]);       \
          hsq[m] = __builtin_elementwise_fma(wh[k - m], vb, hsq[m]);       \
        }                                                                  \
      if (k == 7) __builtin_amdgcn_sched_barrier(0);                       \
    }                                                                      \
    _Pragma("unroll")                                                      \
    for (int m = 0; m < 4; ++m) {                                          \
      const float hmp = (float)hpt[m][0], hmt = (float)hpt[m][1];          \
      const float s2f = (float)hsq[m][0], scf = (float)hsq[m][1];          \
      const float mp2 = hmp * hmp, mt2 = hmt * hmt, mct = hmp * hmt;       \
      const float ssum = fmaxf(s2f - mp2 - mt2, 0.f);                      \
      const float scv = scf - mct;                                         \
      const float num = fmaf(2.f, mct, 1.0e-4f) * fmaf(2.f, scv, 9.0e-4f); \
      const float den = (mp2 + mt2 + 1.0e-4f) * (ssum + 9.0e-4f);          \
      sum += num * __builtin_amdgcn_rcpf(den);                             \
    }                                                                      \
  }

  for (int g = 0; g < HB; g += 2 * KR) {  // 8 iterations x 2 groups
    GROUP(g, 0)
    GROUP(g + KR, 1)
  }
#undef GROUP
#undef VACC

  // block reduction of ssim partial sum
#pragma unroll
  for (int off = 32; off > 0; off >>= 1) sum += __shfl_down(sum, off, 64);
  if ((tid & 63) == 0) wsum[tid >> 6] = sum;
  __syncthreads();
  if (tid == 0) {
    float s = 0.f;
#pragma unroll
    for (int k2 = 0; k2 < 8; ++k2) s += wsum[k2];
    partial[blk] = s;
  }
}

__global__ void ssim_fin(const float* __restrict__ partial,
                         float* __restrict__ out, int n) {
  __shared__ double ws[4];
  double s = 0.0;
  for (int idx = threadIdx.x; idx < n; idx += 256) s += (double)partial[idx];
#pragma unroll
  for (int off = 32; off > 0; off >>= 1) s += __shfl_down(s, off, 64);
  if ((threadIdx.x & 63) == 0) ws[threadIdx.x >> 6] = s;
  __syncthreads();
  if (threadIdx.x == 0) {
    double tt = ws[0] + ws[1] + ws[2] + ws[3];
    out[0] = (float)(1.0 - tt / 32505856.0);
  }
}

extern "C" void kernel_launch(void* const* d_in, const int* in_sizes, int n_in,
                              void* d_out, int out_size, void* d_ws, size_t ws_size,
                              hipStream_t stream) {
  const float* pred = (const float*)d_in[0];
  const float* tgt  = (const float*)d_in[1];
  float* out        = (float*)d_out;
  float* partial    = (float*)d_ws;   // 992 floats of scratch

  ssim_main<<<dim3(992), dim3(512), 0, stream>>>(pred, tgt, partial);
  ssim_fin<<<dim3(1), dim3(256), 0, stream>>>(partial, out, 992);
}

// Round 17
// 92.524 us; speedup vs baseline: 1.3092x; 1.0214x over previous
//
#include <hip/hip_runtime.h>
#include <math.h>

#define HH 512
#define WW 512
#define HB 64        // band height (8 bands per plane -> grid 992)
#define KR 4         // output rows per group
#define SUB 132      // uint2 slots per sub-array: 2+128+2 (halo+cols);
                     // 2*132 mod 32 == 8 -> write banks s*8+{0..14}: every
                     // bank exactly 2-way per 32-lane phase = FREE (m136).
#define ROWU2 (4 * SUB)     // 528 uint2 per row-tile
#define TILEU2 (4 * ROWU2)  // 2112 uint2 = 16896 B total (single buffer)

// R17: R16 minus the double-buffer. Cross-round occupancy data (34KB->37-51%,
// 68KB->21%) says the scheduler fits only ~2 blocks/CU at 34KB; the single
// 16.9KB f16 tile targets 4 blocks/CU (= 32 waves, wave-capped). Schedule per
// group: [bar_pre | stage (4 ds_writes) | bar_post | H(g) + V(g+1) + prefetch]
// -- V(g+1) is register-only so it sits in the big region; the bar_pre ->
// bar_post region is tiny, so the two barriers cost ~one. Light barriers
// (lgkmcnt only) keep prefetch loads in flight across both (R12-proven).
// f16 staging numerics: absmax 0.0039 << 0.0198, stable since R15.

typedef float v2f __attribute__((ext_vector_type(2)));
typedef _Float16 h2 __attribute__((ext_vector_type(2)));

__device__ __forceinline__ void bar_lgkm() {
  asm volatile("s_waitcnt lgkmcnt(0)" ::: "memory");
  __builtin_amdgcn_s_barrier();
  __builtin_amdgcn_sched_barrier(0);
}

__device__ __forceinline__ unsigned pk16(float a, float b) {
  return __builtin_bit_cast(unsigned, __builtin_amdgcn_cvt_pkrtz(a, b));
}

__global__ __launch_bounds__(512, 1)
void ssim_main(const float* __restrict__ Pg, const float* __restrict__ Tg,
               float* __restrict__ partial) {
  __shared__ __align__(16) uint2 S2[TILEU2];   // 16896 B
  __shared__ float wsum[8];

  const int tid = threadIdx.x;            // vertical pass: column 0..511
  const int blk = blockIdx.x;
  const int plane = blk >> 3;
  const int band  = blk & 7;
  const int o0 = band * HB;               // first output row of band
  const float* __restrict__ P = Pg + (size_t)plane * (HH * WW);
  const float* __restrict__ T = Tg + (size_t)plane * (HH * WW);

  // zero tile once: halo slots (0,1,130,131 per sub-array) must stay 0
  // forever; interior slots 2..129 are fully overwritten every group.
  {
    const uint2 z = make_uint2(0u, 0u);
    for (int idx = tid; idx < TILEU2; idx += 512) S2[idx] = z;
  }

  // Gaussian weights, computed in double then rounded to f32 (matches jnp f32)
  float w[11];
  {
    double g[11], s = 0.0;
#pragma unroll
    for (int k = 0; k < 11; ++k) {
      double c = (double)(k - 5);
      g[k] = exp(-c * c / 4.5);
      s += g[k];
    }
#pragma unroll
    for (int k = 0; k < 11; ++k)
      w[k] = __uint_as_float(__builtin_amdgcn_readfirstlane(
                 __float_as_uint((float)(g[k] / s))));
  }
  // f16 weight pairs for the packed H-pass
  h2 wh[11];
#pragma unroll
  for (int k = 0; k < 11; ++k) {
    const _Float16 hw = (_Float16)w[k];
    wh[k][0] = hw; wh[k][1] = hw;
  }

  float sum = 0.f;
  const int jr = tid >> 7;                // H-pass: row within group (0..3)
  const int q  = tid & 127;               // H-pass: 4-col block (cols 4q..4q+3)
  uint2* const rdbase = &S2[jr * ROWU2 + q + 2];
  uint2* const wrbase = &S2[(tid & 3) * SUB + (tid >> 2) + 2];

  // ---- rotating register ring (R12-proven): pr/tr[i] = input row rbase+i
  // (i=0..9); pn/tn = rows rbase+10..13 in flight. rbase = o0 + g - 5.
  float pr[10], tr[10], pn[4], tn[4];
#pragma unroll
  for (int i = 0; i < 10; ++i) {
    const int r = o0 - 5 + i;
    const bool v = (r >= 0);              // r <= o0+4 <= 452 < HH always
    pr[i] = v ? P[(size_t)r * WW + tid] : 0.f;
    tr[i] = v ? T[(size_t)r * WW + tid] : 0.f;
  }
#pragma unroll
  for (int i = 0; i < 4; ++i) {
    const int r = o0 + 5 + i;             // always in [5, 461]
    pn[i] = P[(size_t)r * WW + tid];
    tn[i] = T[(size_t)r * WW + tid];
  }

#define VACC(RI, PV, TV) {                                                 \
      const float p_ = (PV), t_ = (TV);                                   \
      const v2f pt  = {p_, t_};                                           \
      const v2f q23 = {fmaf(t_, t_, p_ * p_), p_ * t_};                   \
      _Pragma("unroll")                                                   \
      for (int j = 0; j < KR; ++j) {                                      \
        if ((RI) - j >= 0 && (RI) - j <= 10) {                            \
          const float wk = w[(RI) - j];                                   \
          const v2f wv = {wk, wk};                                        \
          apt[j] = __builtin_elementwise_fma(wv, pt,  apt[j]);            \
          asq[j] = __builtin_elementwise_fma(wv, q23, asq[j]);            \
        }                                                                 \
      }                                                                   \
    }

// VBLOCK(G): vertical sums for output rows G..G+3 into apt/asq (from ring),
// then rotate ring by 4 and issue the prefetch for rows o0+G+9..+12.
#define VBLOCK(G) {                                                        \
    { const v2f z = {0.f, 0.f};                                            \
      _Pragma("unroll")                                                    \
      for (int j = 0; j < KR; ++j) { apt[j] = z; asq[j] = z; } }           \
    _Pragma("unroll")                                                      \
    for (int ri = 0; ri < 10; ++ri) VACC(ri, pr[ri], tr[ri]);              \
    _Pragma("unroll")                                                      \
    for (int i = 0; i < 4; ++i) VACC(10 + i, pn[i], tn[i]);                \
    _Pragma("unroll")                                                      \
    for (int i = 0; i < 6; ++i) { pr[i] = pr[i + 4]; tr[i] = tr[i + 4]; }  \
    _Pragma("unroll")                                                      \
    for (int i = 0; i < 4; ++i) { pr[6 + i] = pn[i]; tr[6 + i] = tn[i]; }  \
    { const int prow = o0 + (G) + 9;                                       \
      if (prow + 3 < HH) {                                                 \
        _Pragma("unroll")                                                  \
        for (int i = 0; i < 4; ++i) {                                      \
          pn[i] = P[(size_t)(prow + i) * WW + tid];                        \
          tn[i] = T[(size_t)(prow + i) * WW + tid];                        \
        }                                                                  \
      } else {                                                             \
        _Pragma("unroll")                                                  \
        for (int i = 0; i < 4; ++i) {                                      \
          const int r = prow + i;                                          \
          const bool v = r < HH;                                           \
          pn[i] = v ? P[(size_t)r * WW + tid] : 0.f;                       \
          tn[i] = v ? T[(size_t)r * WW + tid] : 0.f;                       \
        }                                                                  \
      } }                                                                  \
  }

  v2f apt[KR], asq[KR];
  VBLOCK(0)                               // V for group 0; prefetch group 1

  for (int g = 0; g < HB; g += KR) {      // 16 groups of 4 output rows
    bar_lgkm();        // prior group's H reads done (g=0: zero-init visible)
#pragma unroll
    for (int j = 0; j < KR; ++j)
      wrbase[j * ROWU2] = make_uint2(pk16(apt[j][0], apt[j][1]),
                                     pk16(asq[j][0], asq[j][1]));
    bar_lgkm();        // stage visible to all waves
    // ---- big region: H(g) + SSIM + V(g+1) + prefetch (reg-only) ----
    h2 hpt[4], hsq[4];
    { const h2 z = {(_Float16)0.f, (_Float16)0.f};
#pragma unroll
      for (int m = 0; m < 4; ++m) { hpt[m] = z; hsq[m] = z; } }
#pragma unroll
    for (int k = 0; k < 14; ++k) {
      const int d = k - 5;
      const int s = d & 3;
      const int o = (d - s) >> 2;
      const uint2 vv = rdbase[s * SUB + o];
      const h2 va = __builtin_bit_cast(h2, vv.x);
      const h2 vb = __builtin_bit_cast(h2, vv.y);
#pragma unroll
      for (int m = 0; m < 4; ++m)
        if (k - m >= 0 && k - m <= 10) {
          hpt[m] = __builtin_elementwise_fma(wh[k - m], va, hpt[m]);
          hsq[m] = __builtin_elementwise_fma(wh[k - m], vb, hsq[m]);
        }
    }
#pragma unroll
    for (int m = 0; m < 4; ++m) {
      const float hmp = (float)hpt[m][0], hmt = (float)hpt[m][1];
      const float s2f = (float)hsq[m][0], scf = (float)hsq[m][1];
      const float mp2 = hmp * hmp, mt2 = hmt * hmt, mct = hmp * hmt;
      const float ssum = fmaxf(s2f - mp2 - mt2, 0.f);
      const float scv = scf - mct;
      const float num = fmaf(2.f, mct, 1.0e-4f) * fmaf(2.f, scv, 9.0e-4f);
      const float den = (mp2 + mt2 + 1.0e-4f) * (ssum + 9.0e-4f);
      sum += num * __builtin_amdgcn_rcpf(den);
    }
    if (g + KR < HB) VBLOCK(g + KR)       // V for next group (reg-only)
  }
#undef VBLOCK
#undef VACC

  // block reduction of ssim partial sum
#pragma unroll
  for (int off = 32; off > 0; off >>= 1) sum += __shfl_down(sum, off, 64);
  if ((tid & 63) == 0) wsum[tid >> 6] = sum;
  __syncthreads();
  if (tid == 0) {
    float s = 0.f;
#pragma unroll
    for (int k2 = 0; k2 < 8; ++k2) s += wsum[k2];
    partial[blk] = s;
  }
}

__global__ void ssim_fin(const float* __restrict__ partial,
                         float* __restrict__ out, int n) {
  __shared__ double ws[4];
  double s = 0.0;
  for (int idx = threadIdx.x; idx < n; idx += 256) s += (double)partial[idx];
#pragma unroll
  for (int off = 32; off > 0; off >>= 1) s += __shfl_down(s, off, 64);
  if ((threadIdx.x & 63) == 0) ws[threadIdx.x >> 6] = s;
  __syncthreads();
  if (threadIdx.x == 0) {
    double tt = ws[0] + ws[1] + ws[2] + ws[3];
    out[0] = (float)(1.0 - tt / 32505856.0);
  }
}

extern "C" void kernel_launch(void* const* d_in, const int* in_sizes, int n_in,
                              void* d_out, int out_size, void* d_ws, size_t ws_size,
                              hipStream_t stream) {
  const float* pred = (const float*)d_in[0];
  const float* tgt  = (const float*)d_in[1];
  float* out        = (float*)d_out;
  float* partial    = (float*)d_ws;   // 992 floats of scratch

  ssim_main<<<dim3(992), dim3(512), 0, stream>>>(pred, tgt, partial);
  ssim_fin<<<dim3(1), dim3(256), 0, stream>>>(partial, out, 992);
}